// Round 6
// baseline (450.306 us; speedup 1.0000x reference)
//
#include <hip/hip_runtime.h>

typedef unsigned short u16;
typedef unsigned int   u32;
typedef unsigned long long u64;

typedef __bf16 bf16x8 __attribute__((ext_vector_type(8)));
typedef float  f32x4  __attribute__((ext_vector_type(4)));
typedef u16    u16x4  __attribute__((ext_vector_type(4)));
typedef u16    u16x8  __attribute__((ext_vector_type(8)));

#define IN_F   4096
#define OUT_F  11008
#define TOKENS 4096

#define BM 256
#define BN 128
#define BK 32
#define MT (TOKENS / BM)   // 16
#define NT (OUT_F / BN)    // 86
#define KTILES (IN_F / BK) // 128

// f32 -> bf16 round-to-nearest-even (exact for integers 0..255)
__device__ __forceinline__ u16 f2bf(float f) {
    u32 u = __float_as_uint(f);
    return (u16)((u + 0x7FFFu + ((u >> 16) & 1u)) >> 16);
}

// direct global->LDS async copy, 16B per lane; LDS dest = wave-uniform base + lane*16
#define GLOAD_LDS16(g, l)                                                        \
    __builtin_amdgcn_global_load_lds(                                            \
        (const __attribute__((address_space(1))) u32*)(u64)(g),                  \
        (__attribute__((address_space(3))) u32*)(u64)(l), 16, 0, 0)

#define BAR() __builtin_amdgcn_s_barrier()
#define VM(N) asm volatile("s_waitcnt vmcnt(" #N ")" ::: "memory")

// ---------------- prep_x: f32 -> bf16, plus per-row f32 sum ----------------
__global__ __launch_bounds__(256) void prep_x_kernel(
    const float* __restrict__ x, u16* __restrict__ xb, float* __restrict__ rowsum) {
    const int row = blockIdx.x;
    const int tid = threadIdx.x;
    const float4* xr = reinterpret_cast<const float4*>(x + (size_t)row * IN_F);
    u16x4* xo = reinterpret_cast<u16x4*>(xb + (size_t)row * IN_F);
    float s = 0.f;
#pragma unroll
    for (int i = 0; i < 4; ++i) {
        float4 v = xr[tid * 4 + i];
        s += v.x + v.y + v.z + v.w;
        u16x4 o;
        o[0] = f2bf(v.x); o[1] = f2bf(v.y); o[2] = f2bf(v.z); o[3] = f2bf(v.w);
        xo[tid * 4 + i] = o;
    }
#pragma unroll
    for (int off = 32; off > 0; off >>= 1) s += __shfl_down(s, off, 64);
    __shared__ float wsum[4];
    if ((tid & 63) == 0) wsum[tid >> 6] = s;
    __syncthreads();
    if (tid == 0) rowsum[row] = wsum[0] + wsum[1] + wsum[2] + wsum[3];
}

// ---------------- prep_w: int32 (0..255) -> bf16 (exact) ----------------
__global__ __launch_bounds__(256) void prep_w_kernel(
    const int* __restrict__ wq, u16* __restrict__ wb) {
    const size_t total8 = (size_t)OUT_F * IN_F / 8;
    size_t i = (size_t)blockIdx.x * blockDim.x + threadIdx.x;
    const size_t stride = (size_t)gridDim.x * blockDim.x;
    const int4* p = reinterpret_cast<const int4*>(wq);
    u16x8* o = reinterpret_cast<u16x8*>(wb);
    for (; i < total8; i += stride) {
        int4 a = p[i * 2];
        int4 b = p[i * 2 + 1];
        u16x8 v;
        v[0] = f2bf((float)a.x); v[1] = f2bf((float)a.y);
        v[2] = f2bf((float)a.z); v[3] = f2bf((float)a.w);
        v[4] = f2bf((float)b.x); v[5] = f2bf((float)b.y);
        v[6] = f2bf((float)b.z); v[7] = f2bf((float)b.w);
        o[i] = v;
    }
}

// ------- qgemm: 256x128, 4 waves x (128x64 each), ring-3, 2 blocks/CU --------
// C[t,o] = scale[o] * (sum_k Xb[t,k]*Wb[o,k] - zero[o]*rowsum[t]) + bias[o]
//
// LDS-BW analysis (the r3-r5 limiter): ds-read bytes/wave/K-tile scales with
// (M_w+N_w), FLOP with M_w*N_w. 64x64/wave (r3-5) = 0.5 read/MFMA -> port-bound
// at ~44%. This kernel: 128x64/wave = 12 reads per 32 MFMA = 0.375 read/MFMA,
// with 2 blocks/CU retained (acc 128 AGPR + ~70 arch < 256 -> 2 waves/SIMD).
//
// One phase per K-tile t (slot s = t%3):
//   STAGE A(t+2),B(t+2) -> slot (t+2)%3  (6 gload_lds/wave)
//   ds-read A(t) af[8], B(t) nh0 bfr[2]
//   BAR ; 16 MFMA ; ds-read B(t) nh1 ; 16 MFMA ; VM(6) ; BAR
// VM(6) retires stage(t+1) (issued 2 phases earlier), leaves stage(t+2).
// LDS: A 3x16KB + B 3x8KB = 72KB -> 2 blocks/CU.
//
// Swizzle (r4-verified, conflicts=0): rows 64B; read 16B-slot ^= (row>>1)&3;
// stage pre-swizzles global source slot (lane&3)^((lane>>3)&3) (rule 21).
// L2 grouping (r5-verified, fetch -47%): XCD x owns 4mt x 43nt, mt-inner.

#define LDA(S)                                                                    \
    _Pragma("unroll") for (int m = 0; m < 8; ++m)                                 \
        af[m] = *(const bf16x8*)((const char*)&AS[S][0] +                         \
            ((wr * 128 + m * 16 + l15) * 64 + ((kq ^ ((l15 >> 1) & 3)) << 4)));

#define LDB(S, NH)                                                                \
    _Pragma("unroll") for (int n = 0; n < 2; ++n)                                 \
        bfr[n] = *(const bf16x8*)((const char*)&BS[S][0] +                        \
            ((wc * 64 + ((NH) * 2 + n) * 16 + l15) * 64 +                         \
             ((kq ^ ((l15 >> 1) & 3)) << 4)));

#define MFMA_H(NH)                                                                \
    __builtin_amdgcn_s_setprio(1);                                                \
    _Pragma("unroll") for (int m = 0; m < 8; ++m)                                 \
    _Pragma("unroll") for (int n = 0; n < 2; ++n)                                 \
        acc[m][(NH) * 2 + n] = __builtin_amdgcn_mfma_f32_16x16x32_bf16(           \
            af[m], bfr[n], acc[m][(NH) * 2 + n], 0, 0, 0);                        \
    __builtin_amdgcn_s_setprio(0);

// A tile = 16 chunks of 1KB; wave w (0..3) stages chunks 4w..4w+3
#define STAGE_A(S, KT)                                                            \
    _Pragma("unroll") for (int j = 0; j < 4; ++j) {                               \
        const u16* g_ = Abase + (size_t)(w * 64 + j * 16 + (lane >> 2)) * IN_F +  \
                        (KT) * BK + sa8;                                          \
        GLOAD_LDS16(g_, (char*)&AS[S][0] + (w * 4 + j) * 1024);                   \
    }

// B tile = 8 chunks of 1KB; wave w stages chunks 2w, 2w+1
#define STAGE_B(S, KT)                                                            \
    _Pragma("unroll") for (int j = 0; j < 2; ++j) {                               \
        const u16* g_ = Bbase + (size_t)(w * 32 + j * 16 + (lane >> 2)) * IN_F +  \
                        (KT) * BK + sa8;                                          \
        GLOAD_LDS16(g_, (char*)&BS[S][0] + (w * 2 + j) * 1024);                   \
    }

// full steady phase: tile T in slot S, stage tile T+2 into slot SN
#define PHASE(S, SN, T)                                                           \
    STAGE_A(SN, (T) + 2);                                                         \
    STAGE_B(SN, (T) + 2);                                                         \
    LDA(S);                                                                       \
    LDB(S, 0);                                                                    \
    BAR();                                                                        \
    MFMA_H(0);                                                                    \
    LDB(S, 1);                                                                    \
    MFMA_H(1);                                                                    \
    VM(6);                                                                        \
    BAR();

__global__ __launch_bounds__(256, 2) void qgemm_kernel(
    const u16* __restrict__ Xb, const u16* __restrict__ Wb,
    const float* __restrict__ rowsum, const float* __restrict__ scale,
    const float* __restrict__ zero, const float* __restrict__ bias,
    float* __restrict__ out) {
    __shared__ u16 AS[3][BM * BK];  // 3 x 16KB
    __shared__ u16 BS[3][BN * BK];  // 3 x 8KB   (72KB total -> 2 blocks/CU)

    // XCD-region grid map: xcd owns 4mt x 43nt, mt-inner for L2 reuse
    const int bid = blockIdx.x;
    const int xcd = bid & 7;
    const int g   = bid >> 3;            // 0..171
    const int mt  = (xcd >> 1) * 4 + (g & 3);
    const int nt  = (xcd & 1) * 43 + (g >> 2);

    const int tid  = threadIdx.x;
    const int w    = tid >> 6;        // wave 0..3
    const int lane = tid & 63;
    const int wr   = w >> 1;          // wave row half 0..1 (128 rows each)
    const int wc   = w & 1;           // wave col half 0..1 (64 cols each)
    const int l15  = lane & 15;
    const int kq   = lane >> 4;       // 0..3 (8-elem K slot)
    // stage source swizzle: LDS slot lane&3 at chunk-row lane>>2 must hold
    // global slot (lane&3) ^ ((row>>1)&3) = (lane&3) ^ ((lane>>3)&3)
    const int sa8  = (((lane & 3) ^ ((lane >> 3) & 3)) << 3);  // in u16 units

    const u16* Abase = Xb + (size_t)mt * BM * IN_F;
    const u16* Bbase = Wb + (size_t)nt * BN * IN_F;

    bf16x8 af[8];
    bf16x8 bfr[2];
    f32x4 acc[8][4];
    const f32x4 zf = {0.f, 0.f, 0.f, 0.f};
#pragma unroll
    for (int m = 0; m < 8; ++m)
#pragma unroll
        for (int n = 0; n < 4; ++n) acc[m][n] = zf;

    // ---- prologue: stage tiles 0,1 into slots 0,1; retire stage(0) ----
    STAGE_A(0, 0);
    STAGE_B(0, 0);
    STAGE_A(1, 1);
    STAGE_B(1, 1);
    VM(6);   // stage(0) landed; stage(1) in flight
    BAR();

    // ---- steady loop: 42 groups x 3 tiles = tiles 0..125 ----
    for (int i = 0; i < 42; ++i) {
        const int t = 3 * i;
        PHASE(0, 2, t);
        PHASE(1, 0, t + 1);
        PHASE(2, 1, t + 2);
    }

    // ---- peeled: tile 126 (slot 0), tile 127 (slot 1) ----
    LDA(0);
    LDB(0, 0);
    BAR();
    MFMA_H(0);
    LDB(0, 1);
    MFMA_H(1);
    VM(0);   // retire stage(127)
    BAR();
    LDA(1);
    LDB(1, 0);
    BAR();
    MFMA_H(0);
    LDB(1, 1);
    MFMA_H(1);

    // ---- epilogue: C/D layout col = lane&15, row = (lane>>4)*4 + j ----
    const int rowt = mt * BM + wr * 128;
    const int colt = nt * BN + wc * 64;

    float rs[8][4];
#pragma unroll
    for (int m = 0; m < 8; ++m)
#pragma unroll
        for (int j = 0; j < 4; ++j)
            rs[m][j] = rowsum[rowt + m * 16 + kq * 4 + j];

#pragma unroll
    for (int n = 0; n < 4; ++n) {
        const int col = colt + n * 16 + l15;
        const float sc = scale[col];
        const float zp = zero[col];
        const float bs = bias[col];
#pragma unroll
        for (int m = 0; m < 8; ++m) {
            const int rb = rowt + m * 16 + kq * 4;
#pragma unroll
            for (int j = 0; j < 4; ++j) {
                out[(size_t)(rb + j) * OUT_F + col] =
                    sc * (acc[m][n][j] - zp * rs[m][j]) + bs;
            }
        }
    }
}

extern "C" void kernel_launch(void* const* d_in, const int* in_sizes, int n_in,
                              void* d_out, int out_size, void* d_ws, size_t ws_size,
                              hipStream_t stream) {
    const float* x     = (const float*)d_in[0];
    const int*   wq    = (const int*)d_in[1];
    const float* scale = (const float*)d_in[2];
    const float* zero  = (const float*)d_in[3];
    const float* bias  = (const float*)d_in[4];
    float* out = (float*)d_out;

    // workspace layout: Wb (90.2 MB) | Xb (33.6 MB) | rowsum (16 KB)
    char* ws = (char*)d_ws;
    u16* Wb = (u16*)ws;
    u16* Xb = (u16*)(ws + (size_t)OUT_F * IN_F * 2);
    float* rowsum = (float*)(ws + (size_t)OUT_F * IN_F * 2 + (size_t)TOKENS * IN_F * 2);

    prep_w_kernel<<<2048, 256, 0, stream>>>(wq, Wb);
    prep_x_kernel<<<TOKENS, 256, 0, stream>>>(x, Xb, rowsum);
    qgemm_kernel<<<MT * NT, 256, 0, stream>>>(Xb, Wb, rowsum, scale, zero, bias, out);
}

// Round 7
// 257.123 us; speedup vs baseline: 1.7513x; 1.7513x over previous
//
#include <hip/hip_runtime.h>

typedef unsigned short u16;
typedef unsigned int   u32;
typedef unsigned long long u64;
typedef signed char    i8;

typedef int   i32x4 __attribute__((ext_vector_type(4)));

#define IN_F   4096
#define OUT_F  11008
#define TOKENS 4096

#define BM 256
#define BN 128
#define BKQ 64               // K per tile in i8 elems = 64B rows (same bytes as r6)
#define MT (TOKENS / BM)     // 16
#define NT (OUT_F / BN)      // 86
#define KT64 (IN_F / BKQ)    // 64 phases

// direct global->LDS async copy, 16B per lane; LDS dest = wave-uniform base + lane*16
#define GLOAD_LDS16(g, l)                                                        \
    __builtin_amdgcn_global_load_lds(                                            \
        (const __attribute__((address_space(1))) u32*)(u64)(g),                  \
        (__attribute__((address_space(3))) u32*)(u64)(l), 16, 0, 0)

#define BAR() __builtin_amdgcn_s_barrier()
#define VM(N) asm volatile("s_waitcnt vmcnt(" #N ")" ::: "memory")

__device__ __forceinline__ int pack4(int a, int b, int c, int d) {
    return (a & 255) | ((b & 255) << 8) | ((c & 255) << 16) | (d << 24);
}

// ------- prep_x: f32 -> i8 per-row symmetric quant + exact f32 rowsum --------
__global__ __launch_bounds__(256) void prep_x_kernel(
    const float* __restrict__ x, i8* __restrict__ xq,
    float* __restrict__ rowsum, float* __restrict__ rowscale) {
    const int row = blockIdx.x;
    const int tid = threadIdx.x;
    const float4* xr = reinterpret_cast<const float4*>(x + (size_t)row * IN_F);
    float4 v[4];
    float s = 0.f, mx = 0.f;
#pragma unroll
    for (int i = 0; i < 4; ++i) {
        v[i] = xr[tid * 4 + i];
        s += v[i].x + v[i].y + v[i].z + v[i].w;
        mx = fmaxf(mx, fmaxf(fmaxf(fabsf(v[i].x), fabsf(v[i].y)),
                             fmaxf(fabsf(v[i].z), fabsf(v[i].w))));
    }
#pragma unroll
    for (int off = 32; off > 0; off >>= 1) {
        s += __shfl_down(s, off, 64);
        mx = fmaxf(mx, __shfl_down(mx, off, 64));
    }
    __shared__ float ss[4], sm[4];
    if ((tid & 63) == 0) { ss[tid >> 6] = s; sm[tid >> 6] = mx; }
    __syncthreads();
    const float tot = ss[0] + ss[1] + ss[2] + ss[3];
    const float m4  = fmaxf(fmaxf(sm[0], sm[1]), fmaxf(sm[2], sm[3]));
    const float mg  = fmaxf(m4, 1e-20f);
    const float inv = 127.0f / mg;
    if (tid == 0) { rowsum[row] = tot; rowscale[row] = mg * (1.0f / 127.0f); }
    int4 o;
    int q[16];
#pragma unroll
    for (int i = 0; i < 4; ++i) {
        q[4 * i + 0] = (int)rintf(v[i].x * inv);
        q[4 * i + 1] = (int)rintf(v[i].y * inv);
        q[4 * i + 2] = (int)rintf(v[i].z * inv);
        q[4 * i + 3] = (int)rintf(v[i].w * inv);
    }
    o.x = pack4(q[0], q[1], q[2], q[3]);
    o.y = pack4(q[4], q[5], q[6], q[7]);
    o.z = pack4(q[8], q[9], q[10], q[11]);
    o.w = pack4(q[12], q[13], q[14], q[15]);
    reinterpret_cast<int4*>(xq + (size_t)row * IN_F)[tid] = o;
}

// ---------------- prep_w: int32 (0..255) -> i8 (wq - 128, exact) ----------------
__global__ __launch_bounds__(256) void prep_w_kernel(
    const int* __restrict__ wq, i8* __restrict__ wb) {
    const size_t total16 = (size_t)OUT_F * IN_F / 16;
    size_t i = (size_t)blockIdx.x * blockDim.x + threadIdx.x;
    const size_t stride = (size_t)gridDim.x * blockDim.x;
    const int4* p = reinterpret_cast<const int4*>(wq);
    int4* o = reinterpret_cast<int4*>(wb);
    for (; i < total16; i += stride) {
        int4 a = p[i * 4], b = p[i * 4 + 1], c = p[i * 4 + 2], d = p[i * 4 + 3];
        int4 v;
        v.x = pack4(a.x - 128, a.y - 128, a.z - 128, a.w - 128);
        v.y = pack4(b.x - 128, b.y - 128, b.z - 128, b.w - 128);
        v.z = pack4(c.x - 128, c.y - 128, c.z - 128, c.w - 128);
        v.w = pack4(d.x - 128, d.y - 128, d.z - 128, d.w - 128);
        o[i] = v;
    }
}

// ------- qgemm: i8 MFMA 16x16x64, 256x128 tile, 4 waves x (128x64), ring-3 ----
// y[t,o] = scale_o*sx_t*S_to + scale_o*(128-zero_o)*rowsum_t + bias_o
// S_to = sum_k xq[t,k]*wq'[o,k]  (exact i32 via mfma_i32_16x16x64_i8)
//
// Byte-identical LDS geometry to r6 (64B rows, verified conflict-free swizzle:
// read 16B-slot ^= (row>>1)&3; stage pre-swizzles global source slot
// (lane&3)^((lane>>3)&3); rule 21 both-sides). K-tile = 64 i8 -> 64 phases
// (half of r6): every per-phase count (6 gloads, 12 ds_reads, 32 MFMA, 2 BAR,
// 1 VM(6)) unchanged, total work per phase 2x FLOP.
// LDS: A 3x16KB + B 3x8KB = 72KB -> 2 blocks/CU; acc 128 + arch ~110 < 256.

#define LDA(S)                                                                    \
    _Pragma("unroll") for (int m = 0; m < 8; ++m)                                 \
        af[m] = *(const i32x4*)((const char*)&AS[S][0] +                          \
            ((wr * 128 + m * 16 + l15) * 64 + ((kq ^ ((l15 >> 1) & 3)) << 4)));

#define LDB(S, NH)                                                                \
    _Pragma("unroll") for (int n = 0; n < 2; ++n)                                 \
        bfr[n] = *(const i32x4*)((const char*)&BS[S][0] +                         \
            ((wc * 64 + ((NH) * 2 + n) * 16 + l15) * 64 +                         \
             ((kq ^ ((l15 >> 1) & 3)) << 4)));

#define MFMA_H(NH)                                                                \
    __builtin_amdgcn_s_setprio(1);                                                \
    _Pragma("unroll") for (int m = 0; m < 8; ++m)                                 \
    _Pragma("unroll") for (int n = 0; n < 2; ++n)                                 \
        acc[m][(NH) * 2 + n] = __builtin_amdgcn_mfma_i32_16x16x64_i8(             \
            af[m], bfr[n], acc[m][(NH) * 2 + n], 0, 0, 0);                        \
    __builtin_amdgcn_s_setprio(0);

// A tile = 16 chunks of 1KB; wave w (0..3) stages chunks 4w..4w+3
#define STAGE_A(S, KT)                                                            \
    _Pragma("unroll") for (int j = 0; j < 4; ++j) {                               \
        const i8* g_ = Abase + (size_t)(w * 64 + j * 16 + (lane >> 2)) * IN_F +   \
                       (KT) * BKQ + sa16;                                         \
        GLOAD_LDS16(g_, (char*)&AS[S][0] + (w * 4 + j) * 1024);                   \
    }

// B tile = 8 chunks of 1KB; wave w stages chunks 2w, 2w+1
#define STAGE_B(S, KT)                                                            \
    _Pragma("unroll") for (int j = 0; j < 2; ++j) {                               \
        const i8* g_ = Bbase + (size_t)(w * 32 + j * 16 + (lane >> 2)) * IN_F +   \
                       (KT) * BKQ + sa16;                                         \
        GLOAD_LDS16(g_, (char*)&BS[S][0] + (w * 2 + j) * 1024);                   \
    }

// full steady phase: tile T in slot S, stage tile T+2 into slot SN=(T+2)%3
#define PHASE(S, SN, T)                                                           \
    STAGE_A(SN, (T) + 2);                                                         \
    STAGE_B(SN, (T) + 2);                                                         \
    LDA(S);                                                                       \
    LDB(S, 0);                                                                    \
    BAR();                                                                        \
    MFMA_H(0);                                                                    \
    LDB(S, 1);                                                                    \
    MFMA_H(1);                                                                    \
    VM(6);                                                                        \
    BAR();

__global__ __launch_bounds__(256, 2) void qgemm_kernel(
    const i8* __restrict__ Xq, const i8* __restrict__ Wqb,
    const float* __restrict__ rowsum, const float* __restrict__ rowscale,
    const float* __restrict__ scale, const float* __restrict__ zero,
    const float* __restrict__ bias, float* __restrict__ out) {
    __shared__ i8 AS[3][BM * BKQ];  // 3 x 16KB
    __shared__ i8 BS[3][BN * BKQ];  // 3 x 8KB  (72KB -> 2 blocks/CU)

    // XCD-region grid map (r5-verified, fetch -47%): xcd owns 4mt x 43nt, mt-inner
    const int bid = blockIdx.x;
    const int xcd = bid & 7;
    const int g   = bid >> 3;            // 0..171
    const int mt  = (xcd >> 1) * 4 + (g & 3);
    const int nt  = (xcd & 1) * 43 + (g >> 2);

    const int tid  = threadIdx.x;
    const int w    = tid >> 6;        // wave 0..3
    const int lane = tid & 63;
    const int wr   = w >> 1;          // wave row half 0..1 (128 rows each)
    const int wc   = w & 1;           // wave col half 0..1 (64 cols each)
    const int l15  = lane & 15;
    const int kq   = lane >> 4;       // 0..3 (16-elem K slot)
    // stage source swizzle: LDS slot lane&3 at chunk-row lane>>2 holds global
    // slot (lane&3) ^ ((row>>1)&3) = (lane&3) ^ ((lane>>3)&3)   [bytes = elems]
    const int sa16 = (((lane & 3) ^ ((lane >> 3) & 3)) << 4);

    const i8* Abase = Xq  + (size_t)mt * BM * IN_F;
    const i8* Bbase = Wqb + (size_t)nt * BN * IN_F;

    i32x4 af[8];
    i32x4 bfr[2];
    i32x4 acc[8][4];
    const i32x4 zi = {0, 0, 0, 0};
#pragma unroll
    for (int m = 0; m < 8; ++m)
#pragma unroll
        for (int n = 0; n < 4; ++n) acc[m][n] = zi;

    // ---- prologue: stage tiles 0,1 into slots 0,1; retire stage(0) ----
    STAGE_A(0, 0);
    STAGE_B(0, 0);
    STAGE_A(1, 1);
    STAGE_B(1, 1);
    VM(6);   // stage(0) landed; stage(1) in flight
    BAR();

    // ---- steady loop: 20 groups x 3 tiles = tiles 0..59 (stages through 61) ----
    for (int i = 0; i < 20; ++i) {
        const int t = 3 * i;
        PHASE(0, 2, t);
        PHASE(1, 0, t + 1);
        PHASE(2, 1, t + 2);
    }
    // ---- peeled: tiles 60,61 (still staging 62,63), then 62,63 ----
    PHASE(0, 2, 60);   // stages 62 -> slot 2
    PHASE(1, 0, 61);   // stages 63 -> slot 0
    // tile 62 (slot 2), no stage
    LDA(2);
    LDB(2, 0);
    BAR();
    MFMA_H(0);
    LDB(2, 1);
    MFMA_H(1);
    VM(0);   // retire stage(63)
    BAR();
    // tile 63 (slot 0), no stage
    LDA(0);
    LDB(0, 0);
    BAR();
    MFMA_H(0);
    LDB(0, 1);
    MFMA_H(1);

    // ---- epilogue: C/D layout col = lane&15, row = (lane>>4)*4 + j ----
    // y = scale*sx*S + scale*(128-zero)*rowsum + bias
    const int rowt = mt * BM + wr * 128;
    const int colt = nt * BN + wc * 64;

    float scn[4], bcn[4], ccn[4];
#pragma unroll
    for (int n = 0; n < 4; ++n) {
        const int col = colt + n * 16 + l15;
        scn[n] = scale[col];
        bcn[n] = scn[n] * (128.0f - zero[col]);
        ccn[n] = bias[col];
    }
#pragma unroll
    for (int m = 0; m < 8; ++m) {
#pragma unroll
        for (int j = 0; j < 4; ++j) {
            const int r = rowt + m * 16 + kq * 4 + j;
            const float rsv = rowsum[r];
            const float sxv = rowscale[r];
#pragma unroll
            for (int n = 0; n < 4; ++n) {
                out[(size_t)r * OUT_F + colt + n * 16 + l15] =
                    scn[n] * (sxv * (float)acc[m][n][j]) + bcn[n] * rsv + ccn[n];
            }
        }
    }
}

extern "C" void kernel_launch(void* const* d_in, const int* in_sizes, int n_in,
                              void* d_out, int out_size, void* d_ws, size_t ws_size,
                              hipStream_t stream) {
    const float* x     = (const float*)d_in[0];
    const int*   wq    = (const int*)d_in[1];
    const float* scale = (const float*)d_in[2];
    const float* zero  = (const float*)d_in[3];
    const float* bias  = (const float*)d_in[4];
    float* out = (float*)d_out;

    // workspace: Wq' i8 (45.1 MB) | Xq i8 (16.8 MB) | rowsum (16 KB) | rowscale (16 KB)
    char* ws = (char*)d_ws;
    i8* Wqb = (i8*)ws;
    i8* Xq  = (i8*)(ws + (size_t)OUT_F * IN_F);
    float* rowsum   = (float*)(ws + (size_t)OUT_F * IN_F + (size_t)TOKENS * IN_F);
    float* rowscale = rowsum + TOKENS;

    prep_w_kernel<<<2048, 256, 0, stream>>>(wq, Wqb);
    prep_x_kernel<<<TOKENS, 256, 0, stream>>>(x, Xq, rowsum, rowscale);
    qgemm_kernel<<<MT * NT, 256, 0, stream>>>(Xq, Wqb, rowsum, rowscale,
                                              scale, zero, bias, out);
}